// Round 19
// baseline (316.927 us; speedup 1.0000x reference)
//
#include <hip/hip_runtime.h>
#include <math.h>

#define NN    100000
#define GG    100
#define FIN   12
#define FOUT  32
#define KD    5
#define CC    4
#define EE    1600000
#define ROWS  108          // 9 blocks * 12 features
#define NBF   782          // fwd coarse bins (128 nodes each; last has 96)
#define NBINS 1564         // fwd bins + rev bins
#define NBC   1024         // blocks in the coarse build (CHUNK=1563, last=1051)
#define CHUNK 1563
#define NSEG  (NBINS * NBC)   // 1601536, exact multiple of 1024

// bf16 helpers (R18): RNE pack, shift unpack. Storage-only precision cut —
// all arithmetic stays fp32.
__device__ __forceinline__ unsigned bfr(float f) {
    unsigned u = __float_as_uint(f);
    return (u + 0x7FFFu + ((u >> 16) & 1u)) >> 16;
}
__device__ __forceinline__ unsigned pack2(float a, float b) {
    return bfr(a) | (bfr(b) << 16);
}
#define BLO(u) __uint_as_float((u) << 16)
#define BHI(u) __uint_as_float((u) & 0xFFFF0000u)

// ---------------- coarse-bucket CSR build ----------------
// R19: segment bases ordered (xcd, bin, seq) -> recA becomes 8 per-XCD
// sub-arrays (each bin-major over that XCD's 128 chunks). Each XCD's write
// footprint = its own contiguous 3.2 MB (< 4 MB L2) -> partial 64B lines
// stay resident until neighbor segments fill them (R15-18 bin-major layout:
// 3.3x write-back amplification on k_place).
// Bin: bin_f = dst>>7 in [0,NBF); bin_r = NBF + (src>>7).
// recA: .x = nbr | (local_node << 17), .y = edge weight.

// P1: per-block LDS histogram -> hist_g[(xcd*NBINS + bin)*128 + seq].
__global__ __launch_bounds__(256) void k_hist(const int* __restrict__ ei,
                                              int* __restrict__ hist_g) {
    __shared__ int hist[NBINS];
    for (int i = threadIdx.x; i < NBINS; i += 256) hist[i] = 0;
    __syncthreads();
    int xcd = blockIdx.x & 7, seq = blockIdx.x >> 3;
    int chunk = (xcd << 7) | seq;          // XCD-contiguous edge ranges (R11)
    int lo = chunk * CHUNK, hi = lo + CHUNK;
    if (hi > EE) hi = EE;
    for (int e = lo + threadIdx.x; e < hi; e += 256) {
        int s = ei[e], d = ei[EE + e];
        atomicAdd(&hist[d >> 7], 1);
        atomicAdd(&hist[NBF + (s >> 7)], 1);
    }
    __syncthreads();
    for (int i = threadIdx.x; i < NBINS; i += 256)
        hist_g[(xcd * NBINS + i) * 128 + seq] = hist[i];
}

// P2: 3-kernel exclusive scan of hist_g[0..NSEG) in place -> segment bases S.
__global__ __launch_bounds__(1024) void k_scan1(int* __restrict__ g,
                                                int* __restrict__ bsum) {
    __shared__ int sh[1024];
    int t = threadIdx.x;
    int i = blockIdx.x * 1024 + t;
    int v = g[i];                      // NSEG is an exact multiple of 1024
    sh[t] = v;
    __syncthreads();
    for (int d = 1; d < 1024; d <<= 1) {
        int x = sh[t];
        if (t >= d) x += sh[t - d];
        __syncthreads();
        sh[t] = x;
        __syncthreads();
    }
    g[i] = sh[t] - v;
    if (t == 1023) bsum[blockIdx.x] = sh[1023];
}

// scan of nb<=2048 block sums, 2 elems/thread (nb = 1564 here).
__global__ __launch_bounds__(1024) void k_scan2(int* __restrict__ bsum, int nb) {
    __shared__ int sh[1024];
    int t = threadIdx.x;
    int a = (2 * t     < nb) ? bsum[2 * t]     : 0;
    int b = (2 * t + 1 < nb) ? bsum[2 * t + 1] : 0;
    int s = a + b;
    sh[t] = s;
    __syncthreads();
    for (int d = 1; d < 1024; d <<= 1) {
        int x = sh[t];
        if (t >= d) x += sh[t - d];
        __syncthreads();
        sh[t] = x;
        __syncthreads();
    }
    int base = sh[t] - s;
    if (2 * t < nb)     bsum[2 * t] = base;
    if (2 * t + 1 < nb) bsum[2 * t + 1] = base + a;
}

__global__ __launch_bounds__(1024) void k_scan3(int* __restrict__ g,
                                                const int* __restrict__ bsum) {
    int i = blockIdx.x * 1024 + threadIdx.x;
    g[i] += bsum[blockIdx.x];
}

// P2b: extract per-(xcd,bin) run starts (runsS, dedicated array: k_subcsr
// must not read the hist_g region, which aliases rec2) and bin totals cnt[b].
// 8 strided reads per thread (NOT R14's 512-deep serial walk).
__global__ void k_binsum(const int* __restrict__ S, int* __restrict__ runsS,
                         int* __restrict__ cnt) {
    int b = blockIdx.x * 256 + threadIdx.x;
    if (b >= NBINS) return;
    int c = 0;
#pragma unroll
    for (int x = 0; x < 8; ++x) {
        int st = S[(x * NBINS + b) * 128];
        runsS[x * NBINS + b] = st;
        int en;
        if (b + 1 < NBINS)      en = S[(x * NBINS + b + 1) * 128];
        else if (x < 7)         en = S[((x + 1) * NBINS) * 128];
        else                    en = 2 * EE;
        c += en - st;
    }
    cnt[b] = c;
}

// P2c: one-block exclusive scan of cnt -> off[0..NBINS]; terminators.
__global__ __launch_bounds__(1024) void k_scanoff(const int* __restrict__ cnt,
                                                  int* __restrict__ off,
                                                  int* __restrict__ off_node) {
    __shared__ int sh[1024];
    int t = threadIdx.x;
    int a = (2 * t     < NBINS) ? cnt[2 * t]     : 0;
    int b = (2 * t + 1 < NBINS) ? cnt[2 * t + 1] : 0;
    int s = a + b;
    sh[t] = s;
    __syncthreads();
    for (int d = 1; d < 1024; d <<= 1) {
        int x = sh[t];
        if (t >= d) x += sh[t - d];
        __syncthreads();
        sh[t] = x;
        __syncthreads();
    }
    int base = sh[t] - s;
    if (2 * t < NBINS)     off[2 * t] = base;
    if (2 * t + 1 < NBINS) off[2 * t + 1] = base + a;
    if (t == 1023) { off[NBINS] = 2 * EE; off_node[2 * NN] = 2 * EE; }
}

// P3: seed LDS cursors from per-(xcd,bin,seq) bases, place records into the
// XCD's own contiguous recA sub-array.
__global__ __launch_bounds__(256) void k_place(const int* __restrict__ ei,
                                               const float* __restrict__ ew,
                                               const int* __restrict__ S,
                                               int2* __restrict__ recA) {
    __shared__ int cur[NBINS];
    int xcd = blockIdx.x & 7, seq = blockIdx.x >> 3;
    int chunk = (xcd << 7) | seq;
    for (int i = threadIdx.x; i < NBINS; i += 256)
        cur[i] = S[(xcd * NBINS + i) * 128 + seq];
    __syncthreads();
    int lo = chunk * CHUNK, hi = lo + CHUNK;
    if (hi > EE) hi = EE;
    for (int e = lo + threadIdx.x; e < hi; e += 256) {
        int s = ei[e], d = ei[EE + e];
        float w = ew[e];
        int pf = atomicAdd(&cur[d >> 7], 1);
        recA[pf] = make_int2(s | ((d & 127) << 17), __float_as_int(w));
        int pr = atomicAdd(&cur[NBF + (s >> 7)], 1);
        recA[pr] = make_int2(d | ((s & 127) << 17), __float_as_int(w));
    }
}

// P4: per-bin counting sort (bin's records = 8 contiguous per-XCD runs) ->
// exact per-node CSR (4B records, bin-contiguous rec2), fused degree sums
// -> dinv, and (rev bins) gA = bf16(dinv_out .* x).
__global__ __launch_bounds__(256) void k_subcsr(
        const int* __restrict__ off, const int* __restrict__ runsS,
        const int2* __restrict__ recA, const float* __restrict__ x,
        int* __restrict__ off_node, int* __restrict__ rec2,
        float* __restrict__ dinv_in, float* __restrict__ dinv_out,
        uint2* __restrict__ gA) {
    __shared__ int   rs[8], re[8];
    __shared__ int   hist[128];
    __shared__ int   lofs[128];
    __shared__ int   cur[128];
    __shared__ float wsum[128];
    __shared__ float dl[128];
    int b = blockIdx.x;
    int t = threadIdx.x;
    if (t < 128) { hist[t] = 0; wsum[t] = 0.f; }
    if (t < 8) {
        int x8 = t;
        rs[t] = runsS[x8 * NBINS + b];
        if (b + 1 < NBINS)  re[t] = runsS[x8 * NBINS + b + 1];
        else if (x8 < 7)    re[t] = runsS[(x8 + 1) * NBINS];
        else                re[t] = 2 * EE;
    }
    __syncthreads();
    for (int r = 0; r < 8; ++r) {
        for (int e = rs[r] + t; e < re[r]; e += 256) {
            int2 rr = recA[e];
            int loc = rr.x >> 17;
            atomicAdd(&hist[loc], 1);
            atomicAdd(&wsum[loc], __int_as_float(rr.y));
        }
    }
    __syncthreads();
    if (t < 128) lofs[t] = hist[t];
    __syncthreads();
    for (int d = 1; d < 128; d <<= 1) {
        int v = 0;
        if (t < 128 && t >= d) v = lofs[t - d];
        __syncthreads();
        if (t < 128) lofs[t] += v;
        __syncthreads();
    }
    bool rev = b >= NBF;
    int base = (rev ? b - NBF : b) * 128;
    int e0 = off[b];
    if (t < 128) {
        int ex = lofs[t] - hist[t];      // exclusive
        lofs[t] = ex;
        cur[t] = 0;
        int node = base + t;
        if (node < NN) {
            off_node[(rev ? NN : 0) + node] = e0 + ex;
            float inv = 1.f / wsum[t];
            dl[t] = inv;
            if (rev) dinv_out[node] = inv;
            else     dinv_in[node]  = inv;
        }
    }
    __syncthreads();
    for (int r = 0; r < 8; ++r) {
        for (int e = rs[r] + t; e < re[r]; e += 256) {
            int rx = recA[e].x;
            int loc = rx >> 17;
            int pos = e0 + lofs[loc] + atomicAdd(&cur[loc], 1);
            rec2[pos] = rx & 0x1FFFF;
        }
    }
    if (rev) {
        __syncthreads();
        for (int i = t; i < 128 * 3; i += 256) {
            int loc = i / 3, cc = i - loc * 3;
            int node = base + loc;
            if (node < NN) {
                float4 v = *(const float4*)(x + (size_t)node * FIN + cc * 4);
                float sc = dl[loc];
                gA[(size_t)node * 3 + cc] =
                    make_uint2(pack2(v.x * sc, v.y * sc), pack2(v.z * sc, v.w * sc));
            }
        }
    }
}

// ---------------- weights + output init + bf16-x build (merged) ----------------

__global__ void k_misc(const float* __restrict__ Wz_in, const float* __restrict__ Wh_in,
                       float* __restrict__ Wz, float* __restrict__ Wh,
                       const float* __restrict__ b_lin, float* __restrict__ out,
                       const float* __restrict__ x, uint2* __restrict__ xb) {
    int t = blockIdx.x * 256 + threadIdx.x;
    if (t < 2 * ROWS * FOUT) {
        int sel = t / (ROWS * FOUT);
        int rem = t - sel * ROWS * FOUT;
        int r = rem / FOUT;
        int f = rem - r * FOUT;
        int b = r / 12;
        int i = r - b * 12;
        const float* Ws = sel ? Wh_in : Wz_in;
        float v;
        if (b == 0)
            v = Ws[(0 * KD + 0) * 44 * 32 + i * 32 + f] + Ws[(1 * KD + 0) * 44 * 32 + i * 32 + f];
        else if (b <= 4)
            v = Ws[(0 * KD + b) * 44 * 32 + i * 32 + f];
        else
            v = Ws[(1 * KD + (b - 4)) * 44 * 32 + i * 32 + f];
        (sel ? Wh : Wz)[r * FOUT + f] = v;
    }
    int u = t - 2 * ROWS * FOUT;
    if (u >= 0 && u < GG * CC) out[u] = b_lin[u & 3];
    if (t < 3 * NN) {
        int n = t / 3, c = t - n * 3;
        float4 v = *(const float4*)(x + (size_t)n * FIN + c * 4);
        xb[(size_t)n * 3 + c] = make_uint2(pack2(v.x, v.y), pack2(v.z, v.w));
    }
}

// ---------------- diffusion gather (R18 form, unchanged) ----------------
// bf16 rows (12 halves = 24B): random-read working set 2.4 MB/direction,
// L2-resident per XCD. XCD direction split (0-3 fwd, 4-7 rev), rec2 LDS
// staging, LREC=2048, 8-wide unrolled edge loop. All arithmetic fp32.
#define LREC 2048
__global__ __launch_bounds__(256) void k_gather(
        const int* __restrict__ off_node, const int* __restrict__ rec2,
        const uint2* __restrict__ gIn, const uint2* __restrict__ hIn,
        const uint2* __restrict__ prevF, const uint2* __restrict__ prevR,
        const float* __restrict__ dinv_in, const float* __restrict__ dinv_out,
        uint2* __restrict__ outF, uint2* __restrict__ outR,
        uint2* __restrict__ gOut, float c) {
    __shared__ int lrec[LREC];
    int xcd = blockIdx.x & 7;
    int grp = blockIdx.x >> 3;             // 0..292
    bool rev = xcd >= 4;
    int dbase = rev ? NN : 0;
    int ub = (grp * 4 + (xcd & 3)) * 256;  // block's first lin
    int lin = ub + threadIdx.x;

    int u1 = ub + 255; if (u1 > 3 * NN - 1) u1 = 3 * NN - 1;
    int node0 = ub / 3, node1 = u1 / 3;
    int w0 = off_node[dbase + node0];
    int w1 = off_node[dbase + node1 + 1];
    int wn = w1 - w0;
    bool useLds = (wn <= LREC);
    if (useLds) {
        for (int i = threadIdx.x; i < wn; i += 256) lrec[i] = rec2[w0 + i];
    }
    __syncthreads();

    if (lin < 3 * NN) {
        int node = lin / 3;
        int ch = lin - node * 3;
        int i0 = dbase + node;
        int e0 = off_node[i0], e1 = off_node[i0 + 1];
        const uint2* in = rev ? hIn : gIn;

        float ax = 0.f, ay = 0.f, az = 0.f, aw = 0.f;
        float bx = 0.f, by = 0.f, bz = 0.f, bw = 0.f;
        if (useLds) {
            int a0 = e0 - w0, a1 = e1 - w0;
            int e = a0;
            for (; e + 7 < a1; e += 8) {
                int n0 = lrec[e],     n1 = lrec[e + 1], n2 = lrec[e + 2], n3 = lrec[e + 3];
                int n4 = lrec[e + 4], n5 = lrec[e + 5], n6 = lrec[e + 6], n7 = lrec[e + 7];
                uint2 v0 = in[(size_t)n0 * 3 + ch];
                uint2 v1 = in[(size_t)n1 * 3 + ch];
                uint2 v2 = in[(size_t)n2 * 3 + ch];
                uint2 v3 = in[(size_t)n3 * 3 + ch];
                uint2 v4 = in[(size_t)n4 * 3 + ch];
                uint2 v5 = in[(size_t)n5 * 3 + ch];
                uint2 v6 = in[(size_t)n6 * 3 + ch];
                uint2 v7 = in[(size_t)n7 * 3 + ch];
                ax += BLO(v0.x); ay += BHI(v0.x); az += BLO(v0.y); aw += BHI(v0.y);
                bx += BLO(v1.x); by += BHI(v1.x); bz += BLO(v1.y); bw += BHI(v1.y);
                ax += BLO(v2.x); ay += BHI(v2.x); az += BLO(v2.y); aw += BHI(v2.y);
                bx += BLO(v3.x); by += BHI(v3.x); bz += BLO(v3.y); bw += BHI(v3.y);
                ax += BLO(v4.x); ay += BHI(v4.x); az += BLO(v4.y); aw += BHI(v4.y);
                bx += BLO(v5.x); by += BHI(v5.x); bz += BLO(v5.y); bw += BHI(v5.y);
                ax += BLO(v6.x); ay += BHI(v6.x); az += BLO(v6.y); aw += BHI(v6.y);
                bx += BLO(v7.x); by += BHI(v7.x); bz += BLO(v7.y); bw += BHI(v7.y);
            }
            for (; e < a1; ++e) {
                int n0 = lrec[e];
                uint2 v0 = in[(size_t)n0 * 3 + ch];
                ax += BLO(v0.x); ay += BHI(v0.x); az += BLO(v0.y); aw += BHI(v0.y);
            }
        } else {
            for (int e = e0; e < e1; ++e) {
                int n0 = rec2[e];
                uint2 v0 = in[(size_t)n0 * 3 + ch];
                ax += BLO(v0.x); ay += BHI(v0.x); az += BLO(v0.y); aw += BHI(v0.y);
            }
        }
        ax += bx; ay += by; az += bz; aw += bw;

        float sc = rev ? c * dinv_in[node] : c;
        ax *= sc; ay *= sc; az *= sc; aw *= sc;

        size_t o = (size_t)node * 3 + ch;
        if (prevF) {
            uint2 p = (rev ? prevR : prevF)[o];
            ax -= BLO(p.x); ay -= BHI(p.x); az -= BLO(p.y); aw -= BHI(p.y);
        }
        (rev ? outR : outF)[o] = make_uint2(pack2(ax, ay), pack2(az, aw));
        if (!rev && gOut) {
            float g = dinv_out[node];
            gOut[o] = make_uint2(pack2(g * ax, g * ay), pack2(g * az, g * aw));
        }
    }
}

// ---------------- epilogue (R18 form, unchanged) ----------------

__global__ __launch_bounds__(256) void k_fused(
        const float* __restrict__ x, const uint2* __restrict__ TS2,
        const float* __restrict__ Wz, const float* __restrict__ Wh,
        const float* __restrict__ bz, const float* __restrict__ bh,
        const float* __restrict__ Wlin, float* __restrict__ out) {
    __shared__ float rows[128][13];
    __shared__ float red[256 * CC];
    int g = blockIdx.x >> 3;
    int seg = blockIdx.x & 7;
    int base = g * 1000 + seg * 125;
    int tid = threadIdx.x;
    int lane = tid & 63;
    int wave = tid >> 6;
    int f0 = __builtin_amdgcn_readfirstlane(wave * 8);   // wave-uniform f-quarter

    float az0[8], ah0[8], az1[8], ah1[8];
#pragma unroll
    for (int fi = 0; fi < 8; ++fi) {
        float vz = bz[f0 + fi], vh = bh[f0 + fi];
        az0[fi] = vz; ah0[fi] = vh; az1[fi] = vz; ah1[fi] = vh;
    }
    bool act1 = (lane + 64) < 125;

    for (int b = 0; b < 9; ++b) {
        __syncthreads();
        if (b == 0) {
            const float* src = x + (size_t)base * FIN;
            for (int q = tid; q < 375; q += 256) {
                float4 v = *(const float4*)(src + q * 4);
                int e = q * 4;
                int n0 = e / 12,       i0 = e - n0 * 12;       rows[n0][i0] = v.x;
                int n1 = (e + 1) / 12, i1 = (e + 1) - n1 * 12; rows[n1][i1] = v.y;
                int n2 = (e + 2) / 12, i2 = (e + 2) - n2 * 12; rows[n2][i2] = v.z;
                int n3 = (e + 3) / 12, i3 = (e + 3) - n3 * 12; rows[n3][i3] = v.w;
            }
        } else {
            const uint2* Tb = TS2 + (size_t)(b - 1) * NN * 3;
            for (int q = tid; q < 375; q += 256) {
                int n = q / 3, cc = q - n * 3;
                uint2 v = Tb[(size_t)(base + n) * 3 + cc];
                rows[n][cc * 4 + 0] = BLO(v.x);
                rows[n][cc * 4 + 1] = BHI(v.x);
                rows[n][cc * 4 + 2] = BLO(v.y);
                rows[n][cc * 4 + 3] = BHI(v.y);
            }
        }
        __syncthreads();
        const float* wzr = Wz + b * 12 * FOUT + f0;
        const float* whr = Wh + b * 12 * FOUT + f0;
#pragma unroll
        for (int i = 0; i < FIN; ++i) {
            float v0 = rows[lane][i];
            float v1 = rows[lane + 64][i];
#pragma unroll
            for (int fi = 0; fi < 8; ++fi) {
                float wz = wzr[i * FOUT + fi];
                float wh = whr[i * FOUT + fi];
                az0[fi] = fmaf(v0, wz, az0[fi]);
                az1[fi] = fmaf(v1, wz, az1[fi]);
                ah0[fi] = fmaf(v0, wh, ah0[fi]);
                ah1[fi] = fmaf(v1, wh, ah1[fi]);
            }
        }
    }

    float o[CC] = {0.f, 0.f, 0.f, 0.f};
#pragma unroll
    for (int fi = 0; fi < 8; ++fi) {
        float z = 1.f / (1.f + __expf(-az0[fi]));
        float e2 = __expf(2.f * ah0[fi]);
        float th = 1.f - 2.f / (e2 + 1.f);
        float hv = fmaxf((1.f - z) * th, 0.f);
#pragma unroll
        for (int c = 0; c < CC; ++c) o[c] = fmaf(hv, Wlin[(f0 + fi) * 4 + c], o[c]);
    }
    if (act1) {
#pragma unroll
        for (int fi = 0; fi < 8; ++fi) {
            float z = 1.f / (1.f + __expf(-az1[fi]));
            float e2 = __expf(2.f * ah1[fi]);
            float th = 1.f - 2.f / (e2 + 1.f);
            float hv = fmaxf((1.f - z) * th, 0.f);
#pragma unroll
            for (int c = 0; c < CC; ++c) o[c] = fmaf(hv, Wlin[(f0 + fi) * 4 + c], o[c]);
        }
    }

#pragma unroll
    for (int c = 0; c < CC; ++c) red[tid * CC + c] = o[c];
    __syncthreads();
    for (int st = 128; st > 0; st >>= 1) {
        if (tid < st) {
#pragma unroll
            for (int c = 0; c < CC; ++c) red[tid * CC + c] += red[(tid + st) * CC + c];
        }
        __syncthreads();
    }
    if (tid == 0) {
#pragma unroll
        for (int c = 0; c < CC; ++c) atomicAdd(out + g * CC + c, red[c] * 0.001f);
    }
}

// ---------------- launch ----------------

extern "C" void kernel_launch(void* const* d_in, const int* in_sizes, int n_in,
                              void* d_out, int out_size, void* d_ws, size_t ws_size,
                              hipStream_t stream) {
    const float* x     = (const float*)d_in[0];
    const int*   ei    = (const int*)d_in[1];
    const float* ew    = (const float*)d_in[2];
    // d_in[3] (batch) unused: graphs are exactly 1000 contiguous nodes
    const float* W_z   = (const float*)d_in[4];
    const float* b_z   = (const float*)d_in[5];
    // d_in[6], d_in[7] (W_r, b_r) unused: R only multiplies the zero hidden state
    const float* W_h   = (const float*)d_in[8];
    const float* b_h   = (const float*)d_in[9];
    const float* W_lin = (const float*)d_in[10];
    const float* b_lin = (const float*)d_in[11];
    float* out = (float*)d_out;

    // ---- workspace layout (~48 MB) ----
    int*   rec2     = (int*)d_ws;                       // 2*EE ints
    unsigned* TSb   = (unsigned*)(rec2 + 2 * (size_t)EE);  // 8 * NN*6 uints (bf16 rows)
    int2*  recA     = (int2*)TSb;                       // ALIAS: 2*EE int2, dead before gather 1
    int*   hist_g   = rec2;                             // ALIAS: NSEG ints (S), dead before k_subcsr writes rec2
    int*   bsumS    = rec2 + NSEG;                      // ALIAS: 1564 ints
    int*   cnt      = bsumS + 2048;                     // ALIAS: NBINS ints (dead before rec2 write)
    unsigned* gAu   = TSb + (size_t)8 * NN * 6 + 1600000;  // past recA span
    unsigned* gBu   = gAu + (size_t)NN * 6;
    unsigned* xbu   = gBu + (size_t)NN * 6;
    float* dinv_in  = (float*)(xbu + (size_t)NN * 6);   // N
    float* dinv_out = dinv_in + NN;                     // N
    float* Wz       = dinv_out + NN;                    // 108*32
    float* Wh       = Wz + ROWS * FOUT;                 // 108*32
    int*   off      = (int*)(Wh + ROWS * FOUT);         // NBINS+1
    int*   off_node = off + NBINS + 1;                  // 2N+1
    int*   runsS    = off_node + 2 * NN + 1;            // 8*NBINS (NOT aliased: live thru k_subcsr)

    uint2* TS2 = (uint2*)TSb;
    uint2* T1o = TS2 + (size_t)0 * NN * 3;
    uint2* T2o = TS2 + (size_t)1 * NN * 3;
    uint2* T3o = TS2 + (size_t)2 * NN * 3;
    uint2* T4o = TS2 + (size_t)3 * NN * 3;
    uint2* T1i = TS2 + (size_t)4 * NN * 3;
    uint2* T2i = TS2 + (size_t)5 * NN * 3;
    uint2* T3i = TS2 + (size_t)6 * NN * 3;
    uint2* T4i = TS2 + (size_t)7 * NN * 3;
    uint2* gA = (uint2*)gAu;
    uint2* gB = (uint2*)gBu;
    uint2* xb = (uint2*)xbu;

    dim3 B(256);
    int nbG = 2344;                            // 293 * 8 — exact for the XCD swizzle
    int nbScan = NSEG / 1024;                  // 1564, exact
    int nbMisc = (3 * NN + 255) / 256;         // covers xb (300k) + weights + out init

    k_hist<<<NBC, B, 0, stream>>>(ei, hist_g);
    k_scan1<<<nbScan, 1024, 0, stream>>>(hist_g, bsumS);
    k_scan2<<<1, 1024, 0, stream>>>(bsumS, nbScan);
    k_scan3<<<nbScan, 1024, 0, stream>>>(hist_g, bsumS);
    k_binsum<<<(NBINS + 255) / 256, B, 0, stream>>>(hist_g, runsS, cnt);
    k_scanoff<<<1, 1024, 0, stream>>>(cnt, off, off_node);
    k_place<<<NBC, B, 0, stream>>>(ei, ew, hist_g, recA);
    k_subcsr<<<NBINS, B, 0, stream>>>(off, runsS, recA, x, off_node, rec2,
                                      dinv_in, dinv_out, gA);

    k_misc<<<nbMisc, B, 0, stream>>>(W_z, W_h, Wz, Wh, b_lin, out, x, xb);

    // Chebyshev diffusion basis (bf16 storage, fp32 math)
    k_gather<<<nbG, B, 0, stream>>>(off_node, rec2, gA, xb,  nullptr, nullptr, dinv_in, dinv_out, T1o, T1i, gB, 1.f);
    k_gather<<<nbG, B, 0, stream>>>(off_node, rec2, gB, T1i, xb,      xb,      dinv_in, dinv_out, T2o, T2i, gA, 2.f);
    k_gather<<<nbG, B, 0, stream>>>(off_node, rec2, gA, T2i, T1o,     T1i,     dinv_in, dinv_out, T3o, T3i, gB, 2.f);
    k_gather<<<nbG, B, 0, stream>>>(off_node, rec2, gB, T3i, T2o,     T2i,     dinv_in, dinv_out, T4o, T4i, nullptr, 2.f);

    k_fused<<<8 * GG, B, 0, stream>>>(x, TS2, Wz, Wh, b_z, b_h, W_lin, out);
}

// Round 20
// 309.356 us; speedup vs baseline: 1.0245x; 1.0245x over previous
//
#include <hip/hip_runtime.h>
#include <math.h>

#define NN    100000
#define GG    100
#define FIN   12
#define FOUT  32
#define KD    5
#define CC    4
#define EE    1600000
#define ROWS  108          // 9 blocks * 12 features
#define NBF   782          // fwd coarse bins (128 nodes each; last has 96)
#define NBINS 1564         // fwd bins + rev bins
#define NBC   1024         // blocks in the coarse build (CHUNK=1563, last=1051)
#define CHUNK 1563
#define NSEG  (NBINS * NBC)   // 1601536 = 1564 * 1024 exactly

// bf16 helpers: RNE pack, shift unpack. Storage-only precision cut — all
// arithmetic stays fp32. Random-gather working set per direction drops
// 4.8 MB -> 2.4 MB (< 4 MB per-XCD L2).
__device__ __forceinline__ unsigned bfr(float f) {
    unsigned u = __float_as_uint(f);
    return (u + 0x7FFFu + ((u >> 16) & 1u)) >> 16;
}
__device__ __forceinline__ unsigned pack2(float a, float b) {
    return bfr(a) | (bfr(b) << 16);
}
#define BLO(u) __uint_as_float((u) << 16)
#define BHI(u) __uint_as_float((u) & 0xFFFF0000u)

// XCD-contiguous chunk remap (R11: contiguous ei/ew reads per XCD).
__device__ __forceinline__ int chunk_of_block(int b) {
    return ((b & 7) << 7) | (b >> 3);      // NBC=1024: xcd*128 + seq
}

// ---------------- coarse-bucket CSR build (R15/R16 structure) ----------------
// Bin layout: bin_f = dst>>7 in [0,NBF); bin_r = NBF + (src>>7).
// recA (bin-major): .x = nbr | (local_node << 17), .y = edge weight.

// P1: per-block LDS histogram -> stores into bin-major hist_g[bin][chunk].
__global__ __launch_bounds__(256) void k_hist(const int* __restrict__ ei,
                                              int* __restrict__ hist_g) {
    __shared__ int hist[NBINS];
    for (int i = threadIdx.x; i < NBINS; i += 256) hist[i] = 0;
    __syncthreads();
    int chunk = chunk_of_block(blockIdx.x);
    int lo = chunk * CHUNK, hi = lo + CHUNK;
    if (hi > EE) hi = EE;
    for (int e = lo + threadIdx.x; e < hi; e += 256) {
        int s = ei[e], d = ei[EE + e];
        atomicAdd(&hist[d >> 7], 1);
        atomicAdd(&hist[NBF + (s >> 7)], 1);
    }
    __syncthreads();
    for (int i = threadIdx.x; i < NBINS; i += 256)
        hist_g[i * NBC + chunk] = hist[i];
}

// P2: 3-kernel exclusive scan of hist_g[0..NSEG) in place -> per-(bin,chunk) bases.
__global__ __launch_bounds__(1024) void k_scan1(int* __restrict__ g,
                                                int* __restrict__ bsum) {
    __shared__ int sh[1024];
    int t = threadIdx.x;
    int i = blockIdx.x * 1024 + t;
    int v = g[i];                      // NSEG is an exact multiple of 1024
    sh[t] = v;
    __syncthreads();
    for (int d = 1; d < 1024; d <<= 1) {
        int x = sh[t];
        if (t >= d) x += sh[t - d];
        __syncthreads();
        sh[t] = x;
        __syncthreads();
    }
    g[i] = sh[t] - v;
    if (t == 1023) bsum[blockIdx.x] = sh[1023];
}

// scan of nb<=2048 block sums, 2 elems/thread (nb = 1564 here).
__global__ __launch_bounds__(1024) void k_scan2(int* __restrict__ bsum, int nb) {
    __shared__ int sh[1024];
    int t = threadIdx.x;
    int a = (2 * t     < nb) ? bsum[2 * t]     : 0;
    int b = (2 * t + 1 < nb) ? bsum[2 * t + 1] : 0;
    int s = a + b;
    sh[t] = s;
    __syncthreads();
    for (int d = 1; d < 1024; d <<= 1) {
        int x = sh[t];
        if (t >= d) x += sh[t - d];
        __syncthreads();
        sh[t] = x;
        __syncthreads();
    }
    int base = sh[t] - s;
    if (2 * t < nb)     bsum[2 * t] = base;
    if (2 * t + 1 < nb) bsum[2 * t + 1] = base + a;
}

// adds block base; extracts bucket offsets off[bin] = scanned[bin*NBC];
// terminates off/off_node with the constant total 2*EE.
__global__ __launch_bounds__(1024) void k_scan3(int* __restrict__ g,
                                                const int* __restrict__ bsum,
                                                int* __restrict__ off,
                                                int* __restrict__ off_node) {
    int i = blockIdx.x * 1024 + threadIdx.x;
    int v = g[i] + bsum[blockIdx.x];
    g[i] = v;
    if ((i & (NBC - 1)) == 0) off[i / NBC] = v;
    if (i == 0) { off[NBINS] = 2 * EE; off_node[2 * NN] = 2 * EE; }
}

// P3: seed LDS cursors from precomputed bases, place records (bin-major recA).
__global__ __launch_bounds__(256) void k_place(const int* __restrict__ ei,
                                               const float* __restrict__ ew,
                                               const int* __restrict__ base_g,
                                               int2* __restrict__ recA) {
    __shared__ int cur[NBINS];
    int chunk = chunk_of_block(blockIdx.x);
    for (int i = threadIdx.x; i < NBINS; i += 256) cur[i] = base_g[i * NBC + chunk];
    __syncthreads();
    int lo = chunk * CHUNK, hi = lo + CHUNK;
    if (hi > EE) hi = EE;
    for (int e = lo + threadIdx.x; e < hi; e += 256) {
        int s = ei[e], d = ei[EE + e];
        float w = ew[e];
        int pf = atomicAdd(&cur[d >> 7], 1);
        recA[pf] = make_int2(s | ((d & 127) << 17), __float_as_int(w));
        int pr = atomicAdd(&cur[NBF + (s >> 7)], 1);
        recA[pr] = make_int2(d | ((s & 127) << 17), __float_as_int(w));
    }
}

// P4: per-bin counting sort by local node -> exact per-node CSR (4B records),
// fused weighted-degree sums -> dinv, and (rev bins) gA = bf16(dinv_out .* x).
__global__ __launch_bounds__(256) void k_subcsr(
        const int* __restrict__ off, const int2* __restrict__ recA,
        const float* __restrict__ x,
        int* __restrict__ off_node, int* __restrict__ rec2,
        float* __restrict__ dinv_in, float* __restrict__ dinv_out,
        uint2* __restrict__ gA) {
    __shared__ int   hist[128];
    __shared__ int   lofs[128];
    __shared__ int   cur[128];
    __shared__ float wsum[128];
    __shared__ float dl[128];
    int b = blockIdx.x;
    int t = threadIdx.x;
    if (t < 128) { hist[t] = 0; wsum[t] = 0.f; }
    __syncthreads();
    int e0 = off[b], e1 = off[b + 1];
    for (int e = e0 + t; e < e1; e += 256) {
        int2 r = recA[e];
        int loc = r.x >> 17;
        atomicAdd(&hist[loc], 1);
        atomicAdd(&wsum[loc], __int_as_float(r.y));
    }
    __syncthreads();
    if (t < 128) lofs[t] = hist[t];
    __syncthreads();
    for (int d = 1; d < 128; d <<= 1) {
        int v = 0;
        if (t < 128 && t >= d) v = lofs[t - d];
        __syncthreads();
        if (t < 128) lofs[t] += v;
        __syncthreads();
    }
    bool rev = b >= NBF;
    int base = (rev ? b - NBF : b) * 128;
    if (t < 128) {
        int ex = lofs[t] - hist[t];      // exclusive
        lofs[t] = ex;
        cur[t] = 0;
        int node = base + t;
        if (node < NN) {
            off_node[(rev ? NN : 0) + node] = e0 + ex;
            float inv = 1.f / wsum[t];
            dl[t] = inv;
            if (rev) dinv_out[node] = inv;
            else     dinv_in[node]  = inv;
        }
    }
    __syncthreads();
    for (int e = e0 + t; e < e1; e += 256) {
        int rx = recA[e].x;
        int loc = rx >> 17;
        int pos = e0 + lofs[loc] + atomicAdd(&cur[loc], 1);
        rec2[pos] = rx & 0x1FFFF;
    }
    if (rev) {
        __syncthreads();
        for (int i = t; i < 128 * 3; i += 256) {
            int loc = i / 3, cc = i - loc * 3;
            int node = base + loc;
            if (node < NN) {
                float4 v = *(const float4*)(x + (size_t)node * FIN + cc * 4);
                float sc = dl[loc];
                gA[(size_t)node * 3 + cc] =
                    make_uint2(pack2(v.x * sc, v.y * sc), pack2(v.z * sc, v.w * sc));
            }
        }
    }
}

// ---------------- weights + output init + bf16-x build (merged) ----------------

// Collapse W[2,K,44,32] -> effective [108,32]; seed out with b_lin;
// build xb = bf16 copy of x (gather-side input).
__global__ void k_misc(const float* __restrict__ Wz_in, const float* __restrict__ Wh_in,
                       float* __restrict__ Wz, float* __restrict__ Wh,
                       const float* __restrict__ b_lin, float* __restrict__ out,
                       const float* __restrict__ x, uint2* __restrict__ xb) {
    int t = blockIdx.x * 256 + threadIdx.x;
    if (t < 2 * ROWS * FOUT) {
        int sel = t / (ROWS * FOUT);
        int rem = t - sel * ROWS * FOUT;
        int r = rem / FOUT;
        int f = rem - r * FOUT;
        int b = r / 12;
        int i = r - b * 12;
        const float* Ws = sel ? Wh_in : Wz_in;
        float v;
        if (b == 0)
            v = Ws[(0 * KD + 0) * 44 * 32 + i * 32 + f] + Ws[(1 * KD + 0) * 44 * 32 + i * 32 + f];
        else if (b <= 4)
            v = Ws[(0 * KD + b) * 44 * 32 + i * 32 + f];
        else
            v = Ws[(1 * KD + (b - 4)) * 44 * 32 + i * 32 + f];
        (sel ? Wh : Wz)[r * FOUT + f] = v;
    }
    int u = t - 2 * ROWS * FOUT;
    if (u >= 0 && u < GG * CC) out[u] = b_lin[u & 3];
    if (t < 3 * NN) {
        int n = t / 3, c = t - n * 3;
        float4 v = *(const float4*)(x + (size_t)n * FIN + c * 4);
        xb[(size_t)n * 3 + c] = make_uint2(pack2(v.x, v.y), pack2(v.z, v.w));
    }
}

// ---------------- diffusion gather ----------------
// bf16 rows (12 halves = 24B): random-read working set 2.4 MB/direction,
// fully resident in a 4 MB XCD L2. All arithmetic fp32; rounding only at
// stores. XCD direction split (0-3 fwd, 4-7 rev), rec2 LDS staging (R15),
// LREC=2048 (R16), 8-wide unrolled edge loop.
#define LREC 2048
__global__ __launch_bounds__(256) void k_gather(
        const int* __restrict__ off_node, const int* __restrict__ rec2,
        const uint2* __restrict__ gIn, const uint2* __restrict__ hIn,
        const uint2* __restrict__ prevF, const uint2* __restrict__ prevR,
        const float* __restrict__ dinv_in, const float* __restrict__ dinv_out,
        uint2* __restrict__ outF, uint2* __restrict__ outR,
        uint2* __restrict__ gOut, float c) {
    __shared__ int lrec[LREC];
    int xcd = blockIdx.x & 7;
    int grp = blockIdx.x >> 3;             // 0..292
    bool rev = xcd >= 4;
    int dbase = rev ? NN : 0;
    int ub = (grp * 4 + (xcd & 3)) * 256;  // block's first lin
    int lin = ub + threadIdx.x;

    // block's contiguous rec2 window
    int u1 = ub + 255; if (u1 > 3 * NN - 1) u1 = 3 * NN - 1;
    int node0 = ub / 3, node1 = u1 / 3;
    int w0 = off_node[dbase + node0];
    int w1 = off_node[dbase + node1 + 1];
    int wn = w1 - w0;
    bool useLds = (wn <= LREC);
    if (useLds) {
        for (int i = threadIdx.x; i < wn; i += 256) lrec[i] = rec2[w0 + i];
    }
    __syncthreads();

    if (lin < 3 * NN) {
        int node = lin / 3;
        int ch = lin - node * 3;
        int i0 = dbase + node;
        int e0 = off_node[i0], e1 = off_node[i0 + 1];
        const uint2* in = rev ? hIn : gIn;

        float ax = 0.f, ay = 0.f, az = 0.f, aw = 0.f;
        float bx = 0.f, by = 0.f, bz = 0.f, bw = 0.f;
        if (useLds) {
            int a0 = e0 - w0, a1 = e1 - w0;
            int e = a0;
            for (; e + 7 < a1; e += 8) {
                int n0 = lrec[e],     n1 = lrec[e + 1], n2 = lrec[e + 2], n3 = lrec[e + 3];
                int n4 = lrec[e + 4], n5 = lrec[e + 5], n6 = lrec[e + 6], n7 = lrec[e + 7];
                uint2 v0 = in[(size_t)n0 * 3 + ch];
                uint2 v1 = in[(size_t)n1 * 3 + ch];
                uint2 v2 = in[(size_t)n2 * 3 + ch];
                uint2 v3 = in[(size_t)n3 * 3 + ch];
                uint2 v4 = in[(size_t)n4 * 3 + ch];
                uint2 v5 = in[(size_t)n5 * 3 + ch];
                uint2 v6 = in[(size_t)n6 * 3 + ch];
                uint2 v7 = in[(size_t)n7 * 3 + ch];
                ax += BLO(v0.x); ay += BHI(v0.x); az += BLO(v0.y); aw += BHI(v0.y);
                bx += BLO(v1.x); by += BHI(v1.x); bz += BLO(v1.y); bw += BHI(v1.y);
                ax += BLO(v2.x); ay += BHI(v2.x); az += BLO(v2.y); aw += BHI(v2.y);
                bx += BLO(v3.x); by += BHI(v3.x); bz += BLO(v3.y); bw += BHI(v3.y);
                ax += BLO(v4.x); ay += BHI(v4.x); az += BLO(v4.y); aw += BHI(v4.y);
                bx += BLO(v5.x); by += BHI(v5.x); bz += BLO(v5.y); bw += BHI(v5.y);
                ax += BLO(v6.x); ay += BHI(v6.x); az += BLO(v6.y); aw += BHI(v6.y);
                bx += BLO(v7.x); by += BHI(v7.x); bz += BLO(v7.y); bw += BHI(v7.y);
            }
            for (; e < a1; ++e) {
                int n0 = lrec[e];
                uint2 v0 = in[(size_t)n0 * 3 + ch];
                ax += BLO(v0.x); ay += BHI(v0.x); az += BLO(v0.y); aw += BHI(v0.y);
            }
        } else {
            for (int e = e0; e < e1; ++e) {
                int n0 = rec2[e];
                uint2 v0 = in[(size_t)n0 * 3 + ch];
                ax += BLO(v0.x); ay += BHI(v0.x); az += BLO(v0.y); aw += BHI(v0.y);
            }
        }
        ax += bx; ay += by; az += bz; aw += bw;

        float sc = rev ? c * dinv_in[node] : c;
        ax *= sc; ay *= sc; az *= sc; aw *= sc;

        size_t o = (size_t)node * 3 + ch;
        if (prevF) {
            uint2 p = (rev ? prevR : prevF)[o];
            ax -= BLO(p.x); ay -= BHI(p.x); az -= BLO(p.y); aw -= BHI(p.y);
        }
        (rev ? outR : outF)[o] = make_uint2(pack2(ax, ay), pack2(az, aw));
        if (!rev && gOut) {
            float g = dinv_out[node];
            gOut[o] = make_uint2(pack2(g * ax, g * ay), pack2(g * az, g * aw));
        }
    }
}

// ---------------- epilogue ----------------

// Wave-level feature split + LDS row staging. TS rows are bf16 (unpacked to
// fp32 in LDS); block-0 x term stays exact fp32.
__global__ __launch_bounds__(256) void k_fused(
        const float* __restrict__ x, const uint2* __restrict__ TS2,
        const float* __restrict__ Wz, const float* __restrict__ Wh,
        const float* __restrict__ bz, const float* __restrict__ bh,
        const float* __restrict__ Wlin, float* __restrict__ out) {
    __shared__ float rows[128][13];
    __shared__ float red[256 * CC];
    int g = blockIdx.x >> 3;
    int seg = blockIdx.x & 7;
    int base = g * 1000 + seg * 125;
    int tid = threadIdx.x;
    int lane = tid & 63;
    int wave = tid >> 6;
    int f0 = __builtin_amdgcn_readfirstlane(wave * 8);   // wave-uniform f-quarter

    float az0[8], ah0[8], az1[8], ah1[8];
#pragma unroll
    for (int fi = 0; fi < 8; ++fi) {
        float vz = bz[f0 + fi], vh = bh[f0 + fi];
        az0[fi] = vz; ah0[fi] = vh; az1[fi] = vz; ah1[fi] = vh;
    }
    bool act1 = (lane + 64) < 125;     // second node valid for lanes 0..60

    for (int b = 0; b < 9; ++b) {
        __syncthreads();               // protect rows[] from prior-iter readers
        if (b == 0) {
            const float* src = x + (size_t)base * FIN;
            for (int q = tid; q < 375; q += 256) {    // 125*12 floats = 375 float4
                float4 v = *(const float4*)(src + q * 4);
                int e = q * 4;
                int n0 = e / 12,       i0 = e - n0 * 12;       rows[n0][i0] = v.x;
                int n1 = (e + 1) / 12, i1 = (e + 1) - n1 * 12; rows[n1][i1] = v.y;
                int n2 = (e + 2) / 12, i2 = (e + 2) - n2 * 12; rows[n2][i2] = v.z;
                int n3 = (e + 3) / 12, i3 = (e + 3) - n3 * 12; rows[n3][i3] = v.w;
            }
        } else {
            const uint2* Tb = TS2 + (size_t)(b - 1) * NN * 3;
            for (int q = tid; q < 375; q += 256) {    // 125 nodes x 3 chunks
                int n = q / 3, cc = q - n * 3;
                uint2 v = Tb[(size_t)(base + n) * 3 + cc];
                rows[n][cc * 4 + 0] = BLO(v.x);
                rows[n][cc * 4 + 1] = BHI(v.x);
                rows[n][cc * 4 + 2] = BLO(v.y);
                rows[n][cc * 4 + 3] = BHI(v.y);
            }
        }
        __syncthreads();
        const float* wzr = Wz + b * 12 * FOUT + f0;
        const float* whr = Wh + b * 12 * FOUT + f0;
#pragma unroll
        for (int i = 0; i < FIN; ++i) {
            float v0 = rows[lane][i];
            float v1 = rows[lane + 64][i];   // in-bounds (<=127); masked later
#pragma unroll
            for (int fi = 0; fi < 8; ++fi) {
                float wz = wzr[i * FOUT + fi];   // scalar loads (wave-uniform addr)
                float wh = whr[i * FOUT + fi];
                az0[fi] = fmaf(v0, wz, az0[fi]);
                az1[fi] = fmaf(v1, wz, az1[fi]);
                ah0[fi] = fmaf(v0, wh, ah0[fi]);
                ah1[fi] = fmaf(v1, wh, ah1[fi]);
            }
        }
    }

    float o[CC] = {0.f, 0.f, 0.f, 0.f};
#pragma unroll
    for (int fi = 0; fi < 8; ++fi) {
        float z = 1.f / (1.f + __expf(-az0[fi]));
        float e2 = __expf(2.f * ah0[fi]);
        float th = 1.f - 2.f / (e2 + 1.f);
        float hv = fmaxf((1.f - z) * th, 0.f);
#pragma unroll
        for (int c = 0; c < CC; ++c) o[c] = fmaf(hv, Wlin[(f0 + fi) * 4 + c], o[c]);
    }
    if (act1) {
#pragma unroll
        for (int fi = 0; fi < 8; ++fi) {
            float z = 1.f / (1.f + __expf(-az1[fi]));
            float e2 = __expf(2.f * ah1[fi]);
            float th = 1.f - 2.f / (e2 + 1.f);
            float hv = fmaxf((1.f - z) * th, 0.f);
#pragma unroll
            for (int c = 0; c < CC; ++c) o[c] = fmaf(hv, Wlin[(f0 + fi) * 4 + c], o[c]);
        }
    }

#pragma unroll
    for (int c = 0; c < CC; ++c) red[tid * CC + c] = o[c];
    __syncthreads();
    for (int st = 128; st > 0; st >>= 1) {
        if (tid < st) {
#pragma unroll
            for (int c = 0; c < CC; ++c) red[tid * CC + c] += red[(tid + st) * CC + c];
        }
        __syncthreads();
    }
    if (tid == 0) {
#pragma unroll
        for (int c = 0; c < CC; ++c) atomicAdd(out + g * CC + c, red[c] * 0.001f);
    }
}

// ---------------- launch ----------------

extern "C" void kernel_launch(void* const* d_in, const int* in_sizes, int n_in,
                              void* d_out, int out_size, void* d_ws, size_t ws_size,
                              hipStream_t stream) {
    const float* x     = (const float*)d_in[0];
    const int*   ei    = (const int*)d_in[1];
    const float* ew    = (const float*)d_in[2];
    // d_in[3] (batch) unused: graphs are exactly 1000 contiguous nodes
    const float* W_z   = (const float*)d_in[4];
    const float* b_z   = (const float*)d_in[5];
    // d_in[6], d_in[7] (W_r, b_r) unused: R only multiplies the zero hidden state
    const float* W_h   = (const float*)d_in[8];
    const float* b_h   = (const float*)d_in[9];
    const float* W_lin = (const float*)d_in[10];
    const float* b_lin = (const float*)d_in[11];
    float* out = (float*)d_out;

    // ---- workspace layout (~48 MB) ----
    // [rec2 12.8MB][TSb 19.2MB bf16 basis | recA 25.6MB spans TSb + 6.4MB pad]
    // [gA][gB][xb] bf16 2.4MB each, placed AFTER recA's span (k_subcsr writes
    // gA while recA is still live) [dinv][W][off][off_node]
    int*   rec2     = (int*)d_ws;                       // 2*EE ints
    unsigned* TSb   = (unsigned*)(rec2 + 2 * (size_t)EE);  // 8 * NN*6 uints (bf16 rows)
    int2*  recA     = (int2*)TSb;                       // ALIAS: 2*EE int2, dead before gather 1
    int*   hist_g   = rec2;                             // ALIAS: NSEG ints, dead before k_subcsr writes rec2
    int*   bsumS    = rec2 + NSEG;                      // ALIAS: 1564 ints
    unsigned* gAu   = TSb + (size_t)8 * NN * 6 + 1600000;  // past recA span (pad 6.4MB)
    unsigned* gBu   = gAu + (size_t)NN * 6;
    unsigned* xbu   = gBu + (size_t)NN * 6;
    float* dinv_in  = (float*)(xbu + (size_t)NN * 6);   // N
    float* dinv_out = dinv_in + NN;                     // N
    float* Wz       = dinv_out + NN;                    // 108*32
    float* Wh       = Wz + ROWS * FOUT;                 // 108*32
    int*   off      = (int*)(Wh + ROWS * FOUT);         // NBINS+1
    int*   off_node = off + NBINS + 1;                  // 2N+1

    uint2* TS2 = (uint2*)TSb;
    uint2* T1o = TS2 + (size_t)0 * NN * 3;
    uint2* T2o = TS2 + (size_t)1 * NN * 3;
    uint2* T3o = TS2 + (size_t)2 * NN * 3;
    uint2* T4o = TS2 + (size_t)3 * NN * 3;
    uint2* T1i = TS2 + (size_t)4 * NN * 3;
    uint2* T2i = TS2 + (size_t)5 * NN * 3;
    uint2* T3i = TS2 + (size_t)6 * NN * 3;
    uint2* T4i = TS2 + (size_t)7 * NN * 3;
    uint2* gA = (uint2*)gAu;
    uint2* gB = (uint2*)gBu;
    uint2* xb = (uint2*)xbu;

    dim3 B(256);
    int nbG = 2344;                            // 293 * 8 — exact for the XCD swizzle
    int nbScan = NSEG / 1024;                  // 1564, exact
    int nbMisc = (3 * NN + 255) / 256;         // covers xb (300k) + weights + out init

    k_hist<<<NBC, B, 0, stream>>>(ei, hist_g);
    k_scan1<<<nbScan, 1024, 0, stream>>>(hist_g, bsumS);
    k_scan2<<<1, 1024, 0, stream>>>(bsumS, nbScan);
    k_scan3<<<nbScan, 1024, 0, stream>>>(hist_g, bsumS, off, off_node);
    k_place<<<NBC, B, 0, stream>>>(ei, ew, hist_g, recA);
    k_subcsr<<<NBINS, B, 0, stream>>>(off, recA, x, off_node, rec2, dinv_in, dinv_out, gA);

    k_misc<<<nbMisc, B, 0, stream>>>(W_z, W_h, Wz, Wh, b_lin, out, x, xb);

    // Chebyshev diffusion basis (bf16 storage, fp32 math): per-node gather
    // (LDS-staged rec2), pre-scaled fwd inputs (gA/gB), xb = bf16 x.
    k_gather<<<nbG, B, 0, stream>>>(off_node, rec2, gA, xb,  nullptr, nullptr, dinv_in, dinv_out, T1o, T1i, gB, 1.f);
    k_gather<<<nbG, B, 0, stream>>>(off_node, rec2, gB, T1i, xb,      xb,      dinv_in, dinv_out, T2o, T2i, gA, 2.f);
    k_gather<<<nbG, B, 0, stream>>>(off_node, rec2, gA, T2i, T1o,     T1i,     dinv_in, dinv_out, T3o, T3i, gB, 2.f);
    k_gather<<<nbG, B, 0, stream>>>(off_node, rec2, gB, T3i, T2o,     T2i,     dinv_in, dinv_out, T4o, T4i, nullptr, 2.f);

    k_fused<<<8 * GG, B, 0, stream>>>(x, TS2, Wz, Wh, b_z, b_h, W_lin, out);
}